// Round 4
// baseline (234.200 us; speedup 1.0000x reference)
//
#include <hip/hip_runtime.h>

// LIF/IF activation, T=4, v_th=1, subtractive reset, ATan surrogate (fwd only).
// out = (sum_{t=1..4} H(v_t - 1)) / 4 * safe_scale, with
//   c = relu(x) / safe_scale;  v <- v + c;  s = H(v-1);  v <- v - s.
// Arithmetic replicated step-by-step in fp32 to match the numpy reference
// bit-for-bit (IEEE division, no reciprocal-multiply: a 1-ulp difference in c
// can flip a spike at a threshold crossing, costing 0.375 absmax).
//
// Optimization history:
//   R0  one-shot 1 float4/thread, 32768 blocks:            ~60 us @ 4.4 TB/s
//   R2  grid-stride 8x 16MB-stride + nontemporal stores:    98 us @ 2.0 TB/s (stride killed DRAM locality)
//   R3  one-shot 4 float4/thread contiguous, 8192 blocks:   80 us @ 3.4 TB/s (one-shot waves: latency re-paid per wave)
//   R4  (this) persistent grid-stride, 2048 blocks, 2-stage pipeline.
// Model: one-shot waves live ~5000 cycles for 2 KB moved (queued HBM latency
// + per-wave setup); the 6.6 TB/s fill and 6.3 TB/s copy benchmarks are both
// persistent grid-stride loops. Emulate them: long-lived waves streaming 16
// contiguous-sweep iterations, next load issued before current compute.

#define THREADS 256
#define BLOCKS 2048   // 8 wg/CU on 256 CUs -> 8 waves/SIMD resident

typedef float f32x4 __attribute__((ext_vector_type(4)));

__device__ __forceinline__ float lif_elem(float x, float safe_scale) {
    float c = fmaxf(x, 0.0f) / safe_scale;   // IEEE-correct fp32 division at -O3 (no fast-math)
    float v = 0.0f;
    float cnt = 0.0f;
#pragma unroll
    for (int t = 0; t < 4; ++t) {
        v += c;
        float s = ((v - 1.0f) >= 0.0f) ? 1.0f : 0.0f;  // H(v - v_th), v_th = 1
        v -= s;
        cnt += s;
    }
    return (cnt * 0.25f) * safe_scale;       // mean over T, then rescale (ref order)
}

__device__ __forceinline__ f32x4 lif_vec(f32x4 xv, float ss) {
    f32x4 ov;
    ov.x = lif_elem(xv.x, ss);
    ov.y = lif_elem(xv.y, ss);
    ov.z = lif_elem(xv.z, ss);
    ov.w = lif_elem(xv.w, ss);
    return ov;
}

__global__ __launch_bounds__(THREADS) void lif_kernel(const f32x4* __restrict__ x,
                                                      const float* __restrict__ scale_p,
                                                      f32x4* __restrict__ out,
                                                      int n4) {
    const float ss = fmaxf(scale_p[0], 1e-12f);      // uniform scalar
    const int nth = gridDim.x * THREADS;             // total threads (512K for bench)
    int i = blockIdx.x * THREADS + threadIdx.x;

    if (i >= n4) return;
    // Trip count for this thread (uniform across the grid when n4 % nth == 0,
    // which holds for the bench shape: 8M % 512K == 0 -> 16 iterations).
    int iters = (n4 - 1 - i) / nth + 1;

    // 2-stage software pipeline: the load for iteration k+1 is issued before
    // the compute+store of iteration k, so every wave always has a read in
    // flight while its VALU chain (IEEE div + 4-step LIF) runs.
    f32x4 cur = x[i];
    for (int k = 0; k < iters - 1; ++k) {
        f32x4 nxt = x[i + nth];                      // issue next load first
        out[i] = lif_vec(cur, ss);                   // compute + store current
        cur = nxt;
        i += nth;
    }
    out[i] = lif_vec(cur, ss);                       // drain last stage
}

// Tail handler for n % 4 != 0 (not hit for 4096x8192, kept for safety).
__global__ void lif_tail_kernel(const float* __restrict__ x,
                                const float* __restrict__ scale_p,
                                float* __restrict__ out,
                                int start, int n) {
    int idx = start + blockIdx.x * blockDim.x + threadIdx.x;
    if (idx >= n) return;
    float safe_scale = fmaxf(scale_p[0], 1e-12f);
    out[idx] = lif_elem(x[idx], safe_scale);
}

extern "C" void kernel_launch(void* const* d_in, const int* in_sizes, int n_in,
                              void* d_out, int out_size, void* d_ws, size_t ws_size,
                              hipStream_t stream) {
    const float* x = (const float*)d_in[0];
    const float* scale = (const float*)d_in[1];
    float* out = (float*)d_out;
    int n = in_sizes[0];
    int n4 = n >> 2;

    if (n4 > 0) {
        int blocks = BLOCKS;
        // Never launch more threads than elements (small-n safety).
        long long need = ((long long)n4 + THREADS - 1) / THREADS;
        if (need < blocks) blocks = (int)need;
        lif_kernel<<<blocks, THREADS, 0, stream>>>((const f32x4*)x, scale,
                                                   (f32x4*)out, n4);
    }
    int tail_start = n4 << 2;
    int tail = n - tail_start;
    if (tail > 0) {
        lif_tail_kernel<<<1, 64, 0, stream>>>(x, scale, out, tail_start, n);
    }
}

// Round 6
// 218.352 us; speedup vs baseline: 1.0726x; 1.0726x over previous
//
#include <hip/hip_runtime.h>

// LIF/IF activation, T=4, v_th=1, subtractive reset, ATan surrogate (fwd only).
// out = (sum_{t=1..4} H(v_t - 1)) / 4 * safe_scale, with
//   c = relu(x) / safe_scale;  v <- v + c;  s = H(v-1);  v <- v - s.
// Arithmetic replicated step-by-step in fp32 to match the numpy reference
// bit-for-bit (IEEE division, no reciprocal-multiply: a 1-ulp difference in c
// can flip a spike at a threshold crossing, costing 0.375 absmax). The
// closed form min(4, floor(4c)) is likewise rejected: it differs from the
// sequential fp32 accumulation by ~ulps near the k/4 thresholds, and across
// 33.5M random elements spike flips are near-certain.
//
// Optimization history (kernel dispatch time, effective BW):
//   R0  one-shot 1 float4/thread, 32768 blocks:   ~60-70 us @ ~4 TB/s   <- BEST
//   R2  8-stream 16MB-stride + NT stores:           98 us @ 2.0 TB/s
//   R3  one-shot 4 float4/thread contiguous:        79.8 us @ 3.4 TB/s
//   R4  persistent 2048-blk, 2-stage pipeline:      80.4 us @ 2.5 TB/s
// Conclusion: deeper per-wave MLP is consistently neutral-to-negative here;
// the max-occupancy swarm of tiny one-shot waves is the fastest issue
// structure for this post-fill environment. This revision reverts to R0.
// (R5 was a broker acquisition timeout — this is the same source resubmitted.)

#define THREADS 256

typedef float f32x4 __attribute__((ext_vector_type(4)));

__device__ __forceinline__ float lif_elem(float x, float safe_scale) {
    float c = fmaxf(x, 0.0f) / safe_scale;   // IEEE-correct fp32 division at -O3 (no fast-math)
    float v = 0.0f;
    float cnt = 0.0f;
#pragma unroll
    for (int t = 0; t < 4; ++t) {
        v += c;
        float s = ((v - 1.0f) >= 0.0f) ? 1.0f : 0.0f;  // H(v - v_th), v_th = 1
        v -= s;
        cnt += s;
    }
    return (cnt * 0.25f) * safe_scale;       // mean over T, then rescale (ref order)
}

__global__ __launch_bounds__(THREADS) void lif_kernel(const f32x4* __restrict__ x,
                                                      const float* __restrict__ scale_p,
                                                      f32x4* __restrict__ out,
                                                      int n4) {
    int idx = blockIdx.x * THREADS + threadIdx.x;
    if (idx >= n4) return;
    float ss = fmaxf(scale_p[0], 1e-12f);    // uniform scalar (scalar cache broadcast)
    f32x4 xv = x[idx];
    f32x4 ov;
    ov.x = lif_elem(xv.x, ss);
    ov.y = lif_elem(xv.y, ss);
    ov.z = lif_elem(xv.z, ss);
    ov.w = lif_elem(xv.w, ss);
    out[idx] = ov;
}

// Tail handler for n % 4 != 0 (not hit for 4096x8192, kept for safety).
__global__ void lif_tail_kernel(const float* __restrict__ x,
                                const float* __restrict__ scale_p,
                                float* __restrict__ out,
                                int start, int n) {
    int idx = start + blockIdx.x * blockDim.x + threadIdx.x;
    if (idx >= n) return;
    float safe_scale = fmaxf(scale_p[0], 1e-12f);
    out[idx] = lif_elem(x[idx], safe_scale);
}

extern "C" void kernel_launch(void* const* d_in, const int* in_sizes, int n_in,
                              void* d_out, int out_size, void* d_ws, size_t ws_size,
                              hipStream_t stream) {
    const float* x = (const float*)d_in[0];
    const float* scale = (const float*)d_in[1];
    float* out = (float*)d_out;
    int n = in_sizes[0];
    int n4 = n >> 2;

    if (n4 > 0) {
        int blocks = (n4 + THREADS - 1) / THREADS;   // 32768 for bench shape
        lif_kernel<<<blocks, THREADS, 0, stream>>>((const f32x4*)x, scale,
                                                   (f32x4*)out, n4);
    }
    int tail_start = n4 << 2;
    int tail = n - tail_start;
    if (tail > 0) {
        lif_tail_kernel<<<1, 64, 0, stream>>>(x, scale, out, tail_start, n);
    }
}